// Round 11
// baseline (64.784 us; speedup 1.0000x reference)
//
#include <hip/hip_runtime.h>
#include <hip/hip_cooperative_groups.h>
#include <math.h>

namespace cg = cooperative_groups;

// ChamferLossSplitPID: B=512, N=M=256, D=4, PIDs 0..3.
// out[0] = sum_b(sum_{p=1..3} loss_p)/B ; out[1+b] = (sum_{out_pid==0} |y|)/max(c0,1)/B
//
// R11: R9's proven per-batch body (pid-scatter + sorted-thread mapping,
// 512 threads, unroll-4) made a single COOPERATIVE kernel: grid.sync(), then
// block 0 reduces ws[0..511] -> out[0]. No memset node (R8/R10 lesson: a
// 4-byte memset node replays as a ~40us fill dispatch), no second dispatch.

constexpr int BATCH = 512;
constexpr int NP    = 256;
constexpr float INF2 = 1e30f;

__device__ __forceinline__ float dist2_f4(const float4 a, const float4 b) {
    const float dx = a.x - b.x;
    const float dy = a.y - b.y;
    const float dz = a.z - b.z;
    const float dw = a.w - b.w;
    return dx * dx + dy * dy + dz * dz + dw * dw;
}

__device__ __forceinline__ float wave_reduce_add(float v) {
    #pragma unroll
    for (int off = 32; off > 0; off >>= 1)
        v += __shfl_xor(v, off, 64);
    return v;
}

__device__ __forceinline__ float min_scan(const float4 xp, const float4* seg, int cnt) {
    float m0 = INF2, m1 = INF2, m2 = INF2, m3 = INF2;
    int j = 0;
    for (; j + 4 <= cnt; j += 4) {      // 4 independent LDS loads + dist chains
        const float4 A = seg[j], B = seg[j + 1], C = seg[j + 2], D = seg[j + 3];
        m0 = fminf(m0, dist2_f4(xp, A));
        m1 = fminf(m1, dist2_f4(xp, B));
        m2 = fminf(m2, dist2_f4(xp, C));
        m3 = fminf(m3, dist2_f4(xp, D));
    }
    for (; j < cnt; ++j) m0 = fminf(m0, dist2_f4(xp, seg[j]));
    return fminf(fminf(m0, m1), fminf(m2, m3));
}

__global__ __launch_bounds__(512, 4) void chamfer_pid_kernel(
    const float* __restrict__ target,   // [B, NP, 4]
    const float* __restrict__ reco,     // [B, NP, 4]
    const int*   __restrict__ in_pid,   // [B, NP]
    const int*   __restrict__ out_pid,  // [B, NP]
    float* __restrict__ out,            // [1 + B]
    float* __restrict__ ws)             // [B] per-batch nonzero loss
{
    const int b    = blockIdx.x;
    const int tid  = threadIdx.x;
    const int k    = tid & (NP - 1);
    const int half = tid >> 8;          // 0: x-role, 1: y-role

    __shared__ float4 sxs[NP], sys[NP];
    __shared__ int   s_cx[4], s_cy[4], s_offx[4], s_offy[4];
    __shared__ float s_sxy[4], s_syx[4], s_snx[4], s_sny[4];
    __shared__ float s_wred[8];

    if (tid < 4) {
        s_cx[tid] = 0;    s_cy[tid] = 0;
        s_sxy[tid] = 0.f; s_syx[tid] = 0.f;
        s_snx[tid] = 0.f; s_sny[tid] = 0.f;
    }
    __syncthreads();

    // ---- load + slot-grab (half 0 loads x, half 1 loads y) ----
    float4 pt;
    int pid, slot;
    if (half == 0) {
        pt  = reinterpret_cast<const float4*>(target)[(size_t)b * NP + k];
        pid = in_pid[(size_t)b * NP + k];
        slot = atomicAdd(&s_cx[pid], 1);
    } else {
        pt  = reinterpret_cast<const float4*>(reco)[(size_t)b * NP + k];
        pid = out_pid[(size_t)b * NP + k];
        slot = atomicAdd(&s_cy[pid], 1);
    }
    __syncthreads();

    if (tid == 0) {
        int ox = 0, oy = 0;
        #pragma unroll
        for (int q = 0; q < 4; ++q) {
            s_offx[q] = ox; ox += s_cx[q];
            s_offy[q] = oy; oy += s_cy[q];
        }
    }
    __syncthreads();

    if (half == 0) sxs[s_offx[pid] + slot] = pt;
    else           sys[s_offy[pid] + slot] = pt;
    __syncthreads();

    // ---- phase B: thread k owns SORTED point k (wave-coherent pid) ----
    if (half == 0) {
        const int p = (k >= s_offx[1]) + (k >= s_offx[2]) + (k >= s_offx[3]);
        const float4 xp = sxs[k];
        if (p >= 1) {
            const float nrm = sqrtf(xp.x * xp.x + xp.y * xp.y + xp.z * xp.z + xp.w * xp.w);
            atomicAdd(&s_snx[p], nrm);
            const int cnt = s_cy[p];
            if (cnt > 0) {
                const float mn = min_scan(xp, (const float4*)&sys[s_offy[p]], cnt);
                atomicAdd(&s_sxy[p], sqrtf(mn));   // sqrt(min d2) == min dist
            }
        }
    } else {
        const int p = (k >= s_offy[1]) + (k >= s_offy[2]) + (k >= s_offy[3]);
        const float4 yp = sys[k];
        const float nrm = sqrtf(yp.x * yp.x + yp.y * yp.y + yp.z * yp.z + yp.w * yp.w);
        atomicAdd(&s_sny[p], nrm);                 // pid 0 needed for output 1
        if (p >= 1) {
            const int cnt = s_cx[p];
            if (cnt > 0) {
                const float mn = min_scan(yp, (const float4*)&sxs[s_offx[p]], cnt);
                atomicAdd(&s_syx[p], sqrtf(mn));
            }
        }
    }
    __syncthreads();

    if (tid == 0) {
        float nonzero = 0.0f;
        #pragma unroll
        for (int q = 1; q < 4; ++q) {
            const int cxq = s_cx[q];
            const int cyq = s_cy[q];
            const float n_in  = (float)(cxq > 1 ? cxq : 1);
            const float n_out = (float)(cyq > 1 ? cyq : 1);
            float loss;
            if (cyq == 0) {
                loss = s_snx[q] / n_in;
            } else if (cxq == 0) {
                loss = s_sny[q] / n_out;
            } else {
                loss = 0.5f * (s_sxy[q] / n_out + s_syx[q] / n_in);
            }
            nonzero += loss;
        }
        ws[b] = nonzero;

        const int c0 = s_cy[0];
        const float c0f = (float)(c0 > 1 ? c0 : 1);
        out[1 + b] = (s_sny[0] / c0f) / (float)BATCH;
    }

    // ---- phase C: grid-wide sync, block 0 reduces ws -> out[0] ----
    cg::this_grid().sync();

    if (b == 0) {
        float v = ws[tid];              // 512 threads, one value each
        v = wave_reduce_add(v);
        if ((tid & 63) == 0) s_wred[tid >> 6] = v;
        __syncthreads();
        if (tid == 0) {
            float s = 0.f;
            #pragma unroll
            for (int w = 0; w < 8; ++w) s += s_wred[w];
            out[0] = s / (float)BATCH;
        }
    }
}

extern "C" void kernel_launch(void* const* d_in, const int* in_sizes, int n_in,
                              void* d_out, int out_size, void* d_ws, size_t ws_size,
                              hipStream_t stream) {
    const float* target  = (const float*)d_in[0];
    const float* reco    = (const float*)d_in[1];
    const int*   in_pid  = (const int*)d_in[2];
    const int*   out_pid = (const int*)d_in[3];
    float* out = (float*)d_out;
    float* ws  = (float*)d_ws;

    void* args[] = {(void*)&target, (void*)&reco, (void*)&in_pid, (void*)&out_pid,
                    (void*)&out, (void*)&ws};
    hipLaunchCooperativeKernel((const void*)chamfer_pid_kernel,
                               dim3(BATCH), dim3(512), args, 0, stream);
}

// Round 13
// 17.364 us; speedup vs baseline: 3.7310x; 3.7310x over previous
//
#include <hip/hip_runtime.h>
#include <math.h>

// ChamferLossSplitPID: B=512, N=M=256, D=4, PIDs 0..3.
// out[0] = sum_b(sum_{p=1..3} loss_p)/B ; out[1+b] = (sum_{out_pid==0} |y|)/max(c0,1)/B
//
// R12: two role-blocks per batch (grid=1024 -> 4 blocks/CU -> 100% occupancy),
// each block's two 256-thread halves scan half the opposing segment
// (per-thread trips 64->32), combined via LDS. Per-pid loss decomposes into
// x-side + y-side contributions (both blocks see all counts): ws[2b]+ws[2b+1].
// Structure lessons: 2-kernel graph beats memset-node (R10), coop grid.sync
// (R11), and global-atomic variants (R8).

constexpr int BATCH = 512;
constexpr int NP    = 256;
constexpr float INF2 = 1e30f;

__device__ __forceinline__ float dist2_f4(const float4 a, const float4 b) {
    const float dx = a.x - b.x;
    const float dy = a.y - b.y;
    const float dz = a.z - b.z;
    const float dw = a.w - b.w;
    return dx * dx + dy * dy + dz * dz + dw * dw;
}

__device__ __forceinline__ float min_scan_range(const float4 xp, const float4* seg,
                                                int lo, int hi) {
    float m0 = INF2, m1 = INF2, m2 = INF2, m3 = INF2;
    int j = lo;
    for (; j + 4 <= hi; j += 4) {       // 4 independent LDS loads + dist chains
        const float4 A = seg[j], B = seg[j + 1], C = seg[j + 2], D = seg[j + 3];
        m0 = fminf(m0, dist2_f4(xp, A));
        m1 = fminf(m1, dist2_f4(xp, B));
        m2 = fminf(m2, dist2_f4(xp, C));
        m3 = fminf(m3, dist2_f4(xp, D));
    }
    for (; j < hi; ++j) m0 = fminf(m0, dist2_f4(xp, seg[j]));
    return fminf(fminf(m0, m1), fminf(m2, m3));
}

__global__ __launch_bounds__(512, 8) void chamfer_pid_kernel(
    const float* __restrict__ target,   // [B, NP, 4]
    const float* __restrict__ reco,     // [B, NP, 4]
    const int*   __restrict__ in_pid,   // [B, NP]
    const int*   __restrict__ out_pid,  // [B, NP]
    float* __restrict__ out,            // [1 + B]
    float* __restrict__ ws)             // [2*B] per-(batch,role) contribution
{
    const int bp   = blockIdx.x;
    const int b    = bp >> 1;
    const int role = bp & 1;            // 0: x-role, 1: y-role
    const int tid  = threadIdx.x;
    const int k    = tid & (NP - 1);
    const int half = tid >> 8;          // staging: 0 loads x, 1 loads y

    __shared__ float4 sxs[NP], sys[NP];
    __shared__ int   s_cx[4], s_cy[4], s_offx[4], s_offy[4];
    __shared__ float s_sA[4];           // per-pid sum of min-dists (this role's side)
    __shared__ float s_sN[4];           // per-pid sum of norms (this role's side)
    __shared__ float s_half[NP];        // cross-half min exchange

    if (tid < 4) {
        s_cx[tid] = 0;   s_cy[tid] = 0;
        s_sA[tid] = 0.f; s_sN[tid] = 0.f;
    }
    __syncthreads();

    // ---- staging: identical to R9 (half 0 -> x cloud, half 1 -> y cloud) ----
    float4 pt;
    int pid, slot;
    if (half == 0) {
        pt  = reinterpret_cast<const float4*>(target)[(size_t)b * NP + k];
        pid = in_pid[(size_t)b * NP + k];
        slot = atomicAdd(&s_cx[pid], 1);
    } else {
        pt  = reinterpret_cast<const float4*>(reco)[(size_t)b * NP + k];
        pid = out_pid[(size_t)b * NP + k];
        slot = atomicAdd(&s_cy[pid], 1);
    }
    __syncthreads();

    if (tid == 0) {
        int ox = 0, oy = 0;
        #pragma unroll
        for (int q = 0; q < 4; ++q) {
            s_offx[q] = ox; ox += s_cx[q];
            s_offy[q] = oy; oy += s_cy[q];
        }
    }
    __syncthreads();

    if (half == 0) sxs[s_offx[pid] + slot] = pt;
    else           sys[s_offy[pid] + slot] = pt;
    __syncthreads();

    // ---- phase B: block-uniform role; thread pair (k, k+256) splits the scan ----
    const float4* own    = (role == 0) ? sxs : sys;
    const float4* opp    = (role == 0) ? sys : sxs;
    const int*    ownOff = (role == 0) ? s_offx : s_offy;
    const int*    oppOff = (role == 0) ? s_offy : s_offx;
    const int*    oppCnt = (role == 0) ? s_cy : s_cx;

    const int p = (k >= ownOff[1]) + (k >= ownOff[2]) + (k >= ownOff[3]);
    const float4 q4 = own[k];
    const int cnt = oppCnt[p];

    float mn = INF2;
    if (p >= 1 && cnt > 0) {
        const int h  = (cnt + 1) >> 1;
        const int lo = half ? h : 0;
        const int hi = half ? cnt : h;
        mn = min_scan_range(q4, opp + oppOff[p], lo, hi);
    }
    if (half) s_half[k] = mn;
    __syncthreads();

    if (!half) {
        const float nrm = sqrtf(q4.x * q4.x + q4.y * q4.y + q4.z * q4.z + q4.w * q4.w);
        atomicAdd(&s_sN[p], nrm);                 // all pids (pid0 used by y-role)
        if (p >= 1 && cnt > 0) {
            mn = fminf(mn, s_half[k]);
            atomicAdd(&s_sA[p], sqrtf(mn));       // sqrt(min d2) == min dist
        }
    }
    __syncthreads();

    if (tid == 0) {
        float contrib = 0.0f;
        if (role == 0) {
            #pragma unroll
            for (int q = 1; q < 4; ++q) {
                const int cxq = s_cx[q], cyq = s_cy[q];
                if (cyq == 0)
                    contrib += s_sN[q] / (float)(cxq > 1 ? cxq : 1);       // only_x
                else if (cxq > 0)
                    contrib += 0.5f * s_sA[q] / (float)(cyq > 1 ? cyq : 1); // min_xy/n_out
            }
            ws[2 * b] = contrib;
        } else {
            #pragma unroll
            for (int q = 1; q < 4; ++q) {
                const int cxq = s_cx[q], cyq = s_cy[q];
                if (cyq > 0) {
                    if (cxq == 0)
                        contrib += s_sN[q] / (float)(cyq > 1 ? cyq : 1);       // only_y
                    else
                        contrib += 0.5f * s_sA[q] / (float)(cxq > 1 ? cxq : 1); // min_yx/n_in
                }
            }
            ws[2 * b + 1] = contrib;

            const int c0 = s_cy[0];
            out[1 + b] = (s_sN[0] / (float)(c0 > 1 ? c0 : 1)) / (float)BATCH;
        }
    }
}

__global__ __launch_bounds__(256) void chamfer_reduce_kernel(
    const float* __restrict__ ws,  // [2*B] = 1024 floats
    float* __restrict__ out)       // out[0]
{
    __shared__ float red[4];
    const int i = threadIdx.x;
    const float4 v = reinterpret_cast<const float4*>(ws)[i];
    float s = (v.x + v.y) + (v.z + v.w);
    #pragma unroll
    for (int off = 32; off > 0; off >>= 1)
        s += __shfl_xor(s, off, 64);
    if ((i & 63) == 0) red[i >> 6] = s;
    __syncthreads();
    if (i == 0) {
        out[0] = ((red[0] + red[1]) + (red[2] + red[3])) / (float)BATCH;
    }
}

extern "C" void kernel_launch(void* const* d_in, const int* in_sizes, int n_in,
                              void* d_out, int out_size, void* d_ws, size_t ws_size,
                              hipStream_t stream) {
    const float* target  = (const float*)d_in[0];
    const float* reco    = (const float*)d_in[1];
    const int*   in_pid  = (const int*)d_in[2];
    const int*   out_pid = (const int*)d_in[3];
    float* out = (float*)d_out;
    float* ws  = (float*)d_ws;

    chamfer_pid_kernel<<<2 * BATCH, 512, 0, stream>>>(target, reco, in_pid, out_pid, out, ws);
    chamfer_reduce_kernel<<<1, 256, 0, stream>>>(ws, out);
}

// Round 14
// 16.230 us; speedup vs baseline: 3.9916x; 1.0698x over previous
//
#include <hip/hip_runtime.h>
#include <math.h>

// ChamferLossSplitPID: B=512, N=M=256, D=4, PIDs 0..3.
// out[0] = sum_b(sum_{p=1..3} loss_p)/B ; out[1+b] = (sum_{out_pid==0} |y|)/max(c0,1)/B
//
// R14: R9 structure (1 block/batch, 512 thr, pid-scatter + sorted mapping) with:
//  - expansion-form scan: min dist2 = |x|^2 + 2*min_j(h_j - x.y_j), h = 0.5|y|^2
//    precomputed at scatter -> 5 VALU/iter instead of 9.
//  - per-thread register prefix-sum of segment offsets (one barrier fewer).
//  - global loads issued before the init barrier.
//  - 1-wave reduce kernel (no LDS, no barrier).
// Structure lessons: 2-kernel graph beats memset-node (R10: 28.5), coop
// grid.sync (R11: 64.8), readlane regs (R8: 29.5), dual role-blocks (R12: 17.4).

constexpr int BATCH = 512;
constexpr int NP    = 256;
constexpr float INF2 = 1e30f;

// min over segment of t_j = h_j - x.y_j  (4 independent fmin chains for ILP)
__device__ __forceinline__ float tmin_scan(const float4 xp, const float4* seg,
                                           const float* hseg, int cnt) {
    float m0 = INF2, m1 = INF2, m2 = INF2, m3 = INF2;
    int j = 0;
    for (; j + 4 <= cnt; j += 4) {
        const float4 A = seg[j],     Bq = seg[j + 1];
        const float4 C = seg[j + 2], D  = seg[j + 3];
        const float hA = hseg[j],     hB = hseg[j + 1];
        const float hC = hseg[j + 2], hD = hseg[j + 3];
        m0 = fminf(m0, hA - xp.x * A.x  - xp.y * A.y  - xp.z * A.z  - xp.w * A.w);
        m1 = fminf(m1, hB - xp.x * Bq.x - xp.y * Bq.y - xp.z * Bq.z - xp.w * Bq.w);
        m2 = fminf(m2, hC - xp.x * C.x  - xp.y * C.y  - xp.z * C.z  - xp.w * C.w);
        m3 = fminf(m3, hD - xp.x * D.x  - xp.y * D.y  - xp.z * D.z  - xp.w * D.w);
    }
    for (; j < cnt; ++j) {
        const float4 A = seg[j];
        m0 = fminf(m0, hseg[j] - xp.x * A.x - xp.y * A.y - xp.z * A.z - xp.w * A.w);
    }
    return fminf(fminf(m0, m1), fminf(m2, m3));
}

__global__ __launch_bounds__(512) void chamfer_pid_kernel(
    const float* __restrict__ target,   // [B, NP, 4]
    const float* __restrict__ reco,     // [B, NP, 4]
    const int*   __restrict__ in_pid,   // [B, NP]
    const int*   __restrict__ out_pid,  // [B, NP]
    float* __restrict__ out,            // [1 + B]
    float* __restrict__ ws)             // [B] per-batch nonzero loss
{
    const int b    = blockIdx.x;
    const int tid  = threadIdx.x;
    const int k    = tid & (NP - 1);
    const int half = tid >> 8;          // 0: x-side, 1: y-side

    __shared__ float4 sxs[NP], sys[NP];
    __shared__ float  sxh[NP], syh[NP];     // h = 0.5*|pt|^2 per sorted point
    __shared__ int   s_cx[4], s_cy[4];
    __shared__ float s_sxy[4], s_syx[4], s_snx[4], s_sny[4];

    // ---- issue global loads first (hide HBM latency under init/barrier) ----
    float4 pt;
    int pid;
    if (half == 0) {
        pt  = reinterpret_cast<const float4*>(target)[(size_t)b * NP + k];
        pid = in_pid[(size_t)b * NP + k];
    } else {
        pt  = reinterpret_cast<const float4*>(reco)[(size_t)b * NP + k];
        pid = out_pid[(size_t)b * NP + k];
    }

    if (tid < 4) {
        s_cx[tid] = 0;    s_cy[tid] = 0;
        s_sxy[tid] = 0.f; s_syx[tid] = 0.f;
        s_snx[tid] = 0.f; s_sny[tid] = 0.f;
    }
    __syncthreads();

    const int slot = (half == 0) ? atomicAdd(&s_cx[pid], 1)
                                 : atomicAdd(&s_cy[pid], 1);
    __syncthreads();

    // ---- per-thread register prefix sums (no tid==0 step, no extra barrier) ----
    const int cx0 = s_cx[0], cx1 = s_cx[1], cx2 = s_cx[2], cx3 = s_cx[3];
    const int cy0 = s_cy[0], cy1 = s_cy[1], cy2 = s_cy[2], cy3 = s_cy[3];
    int offx[4], offy[4];
    offx[0] = 0; offx[1] = cx0; offx[2] = cx0 + cx1; offx[3] = cx0 + cx1 + cx2;
    offy[0] = 0; offy[1] = cy0; offy[2] = cy0 + cy1; offy[3] = cy0 + cy1 + cy2;

    const float hpt = 0.5f * (pt.x * pt.x + pt.y * pt.y + pt.z * pt.z + pt.w * pt.w);
    if (half == 0) {
        const int d = offx[pid] + slot;
        sxs[d] = pt; sxh[d] = hpt;
    } else {
        const int d = offy[pid] + slot;
        sys[d] = pt; syh[d] = hpt;
    }
    __syncthreads();

    // ---- phase B: thread k owns SORTED point k of its half's cloud ----
    if (half == 0) {
        const int p = (k >= offx[1]) + (k >= offx[2]) + (k >= offx[3]);
        const float4 xp = sxs[k];
        if (p >= 1) {
            const float x2 = xp.x * xp.x + xp.y * xp.y + xp.z * xp.z + xp.w * xp.w;
            atomicAdd(&s_snx[p], sqrtf(x2));
            const int cnt = (p == 1) ? cy1 : (p == 2) ? cy2 : cy3;
            if (cnt > 0) {
                const float tmin = tmin_scan(xp, &sys[offy[p]], &syh[offy[p]], cnt);
                atomicAdd(&s_sxy[p], sqrtf(fmaxf(x2 + 2.0f * tmin, 0.0f)));
            }
        }
    } else {
        const int p = (k >= offy[1]) + (k >= offy[2]) + (k >= offy[3]);
        const float4 yp = sys[k];
        const float y2 = yp.x * yp.x + yp.y * yp.y + yp.z * yp.z + yp.w * yp.w;
        atomicAdd(&s_sny[p], sqrtf(y2));           // pid 0 needed for output 1
        if (p >= 1) {
            const int cnt = (p == 1) ? cx1 : (p == 2) ? cx2 : cx3;
            if (cnt > 0) {
                const float tmin = tmin_scan(yp, &sxs[offx[p]], &sxh[offx[p]], cnt);
                atomicAdd(&s_syx[p], sqrtf(fmaxf(y2 + 2.0f * tmin, 0.0f)));
            }
        }
    }
    __syncthreads();

    if (tid == 0) {
        float nonzero = 0.0f;
        #pragma unroll
        for (int q = 1; q < 4; ++q) {
            const int cxq = s_cx[q];
            const int cyq = s_cy[q];
            const float n_in  = (float)(cxq > 1 ? cxq : 1);
            const float n_out = (float)(cyq > 1 ? cyq : 1);
            float loss;
            if (cyq == 0) {
                loss = s_snx[q] / n_in;
            } else if (cxq == 0) {
                loss = s_sny[q] / n_out;
            } else {
                loss = 0.5f * (s_sxy[q] / n_out + s_syx[q] / n_in);
            }
            nonzero += loss;
        }
        ws[b] = nonzero;

        const int c0 = s_cy[0];
        out[1 + b] = (s_sny[0] / (float)(c0 > 1 ? c0 : 1)) / (float)BATCH;
    }
}

__global__ __launch_bounds__(64) void chamfer_reduce_kernel(
    const float* __restrict__ ws,  // [B] = 512 floats
    float* __restrict__ out)       // out[0]
{
    const int i = threadIdx.x;     // one wave: 64 threads x 8 values
    const float4 a = reinterpret_cast<const float4*>(ws)[2 * i];
    const float4 c = reinterpret_cast<const float4*>(ws)[2 * i + 1];
    float s = ((a.x + a.y) + (a.z + a.w)) + ((c.x + c.y) + (c.z + c.w));
    #pragma unroll
    for (int off = 32; off > 0; off >>= 1)
        s += __shfl_xor(s, off, 64);
    if (i == 0) out[0] = s / (float)BATCH;
}

extern "C" void kernel_launch(void* const* d_in, const int* in_sizes, int n_in,
                              void* d_out, int out_size, void* d_ws, size_t ws_size,
                              hipStream_t stream) {
    const float* target  = (const float*)d_in[0];
    const float* reco    = (const float*)d_in[1];
    const int*   in_pid  = (const int*)d_in[2];
    const int*   out_pid = (const int*)d_in[3];
    float* out = (float*)d_out;
    float* ws  = (float*)d_ws;

    chamfer_pid_kernel<<<BATCH, 512, 0, stream>>>(target, reco, in_pid, out_pid, out, ws);
    chamfer_reduce_kernel<<<1, 64, 0, stream>>>(ws, out);
}